// Round 8
// baseline (428.363 us; speedup 1.0000x reference)
//
#include <hip/hip_runtime.h>

#define B_ 64
#define T_ 512
#define D_ 1024
#define C_ 32
#define KCH 64                // k-chunk for k_logits LDS tiling
#define CHUNK 16              // logits rows staged per chunk in k_crf (pre[8]/lane)
#define NCHUNK (T_ / CHUNK)   // 32
#define NEG_INF (-1e30f)

__device__ __forceinline__ float bcast0(float v) {
  return __uint_as_float(__builtin_amdgcn_readfirstlane(__float_as_uint(v)));
}
__device__ __forceinline__ float rlane(float v, int l) {
  return __uint_as_float(__builtin_amdgcn_readlane(__float_as_uint(v), l));
}

// ---------------- logits = vectors @ W^T + b (f32, sequential-k fma chain) ----------------
// R7 version (kept): BM=64, grid 512 -> 2 blocks/CU. LDS-tiled, coalesced.
// Per-output k-chain: full D ascending, single f32 accumulator, fixed fma
// order -> logits bit-identical across rounds.
__global__ __launch_bounds__(256) void k_logits(const float* __restrict__ vec,
                                                const float* __restrict__ W,
                                                const float* __restrict__ bias,
                                                float* __restrict__ out) {
  __shared__ __align__(16) float vt[64][KCH + 4];   // 17408 B
  __shared__ __align__(16) float wt[32][KCH + 4];   //  8704 B
  const int tid = threadIdx.x;
  const int cg = tid & 7;   // col base 0..7  (cols cg + 8*cc)
  const int rg = tid >> 3;  // 0..31          (rows r0 + rg + 32*rr)
  const int r0 = blockIdx.x * 64;
  const int sr = tid >> 4;  // 0..15  vec rows sr + 16p
  const int sq = tid & 15;  // float4 slot in the 64-float row chunk
  const int wr = tid >> 3;  // 0..31  W row
  const int wq = tid & 7;   // two float4 slots: wq, wq+8
  float acc[2][4];
#pragma unroll
  for (int a = 0; a < 2; ++a)
#pragma unroll
    for (int bb = 0; bb < 4; ++bb) acc[a][bb] = 0.f;

  for (int c = 0; c < D_ / KCH; ++c) {
    const int k0 = c * KCH;
    __syncthreads();  // previous chunk fully consumed before overwrite
#pragma unroll
    for (int p = 0; p < 4; ++p) {  // vec tile: 4 passes x 16 rows, 256B-coalesced
      const int r = p * 16 + sr;
      float4 v = *(const float4*)(vec + (size_t)(r0 + r) * D_ + k0 + sq * 4);
      *(float4*)&vt[r][sq * 4] = v;
    }
    {  // W tile: 128B-coalesced per 8-lane group
      float4 a = *(const float4*)(W + (size_t)wr * D_ + k0 + wq * 4);
      float4 b2 = *(const float4*)(W + (size_t)wr * D_ + k0 + (wq + 8) * 4);
      *(float4*)&wt[wr][wq * 4] = a;
      *(float4*)&wt[wr][(wq + 8) * 4] = b2;
    }
    __syncthreads();
#pragma unroll 2
    for (int k = 0; k < KCH; k += 4) {
      float4 v[2], w[4];
#pragma unroll
      for (int rr = 0; rr < 2; ++rr) v[rr] = *(const float4*)&vt[rg + rr * 32][k];
#pragma unroll
      for (int cc = 0; cc < 4; ++cc) w[cc] = *(const float4*)&wt[cg + cc * 8][k];
#pragma unroll
      for (int rr = 0; rr < 2; ++rr)
#pragma unroll
        for (int cc = 0; cc < 4; ++cc) {
          acc[rr][cc] = fmaf(v[rr].x, w[cc].x, acc[rr][cc]);
          acc[rr][cc] = fmaf(v[rr].y, w[cc].y, acc[rr][cc]);
          acc[rr][cc] = fmaf(v[rr].z, w[cc].z, acc[rr][cc]);
          acc[rr][cc] = fmaf(v[rr].w, w[cc].w, acc[rr][cc]);
        }
    }
  }
#pragma unroll
  for (int rr = 0; rr < 2; ++rr) {
    const size_t row = (size_t)(r0 + rg + rr * 32);
#pragma unroll
    for (int cc = 0; cc < 4; ++cc) {
      const int c = cg + cc * 8;
      out[row * C_ + c] = acc[rr][cc] + bias[c];  // b32 store: out base only 4B-aligned
    }
  }
}

// ---------------- CRF: forward(+score) and Viterbi(+backtrace) ----------------
// grid 128 x 64 threads (one wave64 per block -> LDS in-order, no barriers).
// R8: one-lgkm-drain-per-step serial loops, built only from pieces validated
// in passing rounds:
//  role0 (forward): scaled-prob space (R2/R4/R5), full-32 fma from LDS float4
//    reads (R4), rcp; s0_sh record + post-loop logZ reconstruction (R5).
//    Chain: a_sh write -> 8x ds_read_b128 -> 32 fma -> rcp -> write.
//  role1 (Viterbi): values-only serial loop (32 plain f32 adds + fmax tree:
//    max is exactly associative -> values bit-equal to np's, R5) with delta
//    ring in LDS; backpointers recomputed IN PARALLEL (R5 phase2: descending
//    '>=' scan == np.argmax first-index ties); R1 backtrace.
//  Same-address 64-lane stores predicated to tid==0; 2-way dup writes kept.
__global__ __launch_bounds__(64) void k_crf(const float* __restrict__ lg,
                                            const int* __restrict__ mask,
                                            const int* __restrict__ tgt,
                                            const float* __restrict__ trans,
                                            const float* __restrict__ st,
                                            const float* __restrict__ et,
                                            float* __restrict__ wsp,
                                            float* __restrict__ tags_out,
                                            float* __restrict__ path_out) {
  __shared__ __align__(16) float dsh[256 * C_];       // delta ring (role1), 32KB
  __shared__ __align__(16) float a_sh[C_];            // forward state (role0)
  __shared__ __align__(16) float Lsh[2][CHUNK * C_];  // staged logits chunks, 4KB
  __shared__ float s0_sh[T_];                         // role0 scale record
  __shared__ int mk_sh[T_];
  __shared__ unsigned char bp[(T_ - 1) * C_];
  __shared__ unsigned char tagb[T_];
  __shared__ unsigned char c8[64 * C_];
  __shared__ int btag[64];

  const int tid = threadIdx.x;
  const int b = blockIdx.x & 63;
  const int role = blockIdx.x >> 6;
  const int j = tid & 31;
  const int h = tid >> 5;
  const float* L = lg + (size_t)b * T_ * C_;
  const int* mk = mask + b * T_;

  // ---- load chunk 0 (rows 0..15) to regs + full mask into LDS ----
  float pre[8];
#pragma unroll
  for (int i = 0; i < 8; ++i) pre[i] = L[i * 64 + tid];
  {
    int4 m0 = *(const int4*)(mk + tid * 4);
    int4 m1 = *(const int4*)(mk + 256 + tid * 4);
    *(int4*)&mk_sh[tid * 4] = m0;
    *(int4*)&mk_sh[256 + tid * 4] = m1;
  }

  if (role == 0) {
    // ================= forward (scaled-prob, LDS state) + score =============
    float ET[32];
#pragma unroll
    for (int i = 0; i < 32; ++i) ET[i] = __expf(trans[i * C_ + j]);
    const float a0j = st[j] + L[j];
    const float m0 = bcast0(a0j);
    float vp = __expf(a0j - m0);  // lanes j and j+32 hold identical values
    a_sh[j] = vp;                 // 2-way dup write, same value (in-order wave)
    // chunk 0 -> F factors. pre[i]: lanes 0-31 = row 2i, lanes 32-63 = row
    // 2i+1; col-0 base is lane 0 / lane 32 respectively. (R5-validated)
#pragma unroll
    for (int i = 0; i < 8; ++i) {
      const float b0v = rlane(pre[i], 0);
      const float b1v = rlane(pre[i], 32);
      const float base = (tid < 32) ? b0v : b1v;
      Lsh[0][i * 64 + tid] = __expf(pre[i] - base);
    }
    for (int c = 0; c < NCHUNK; ++c) {
      if (c < NCHUNK - 1) {
#pragma unroll
        for (int i = 0; i < 8; ++i) pre[i] = L[(c + 1) * (CHUNK * C_) + i * 64 + tid];
      }
      const float* Fs = Lsh[c & 1];
      const int tlo = c ? c * CHUNK : 1;
      const int thi = c * CHUNK + CHUNK;
      for (int t = tlo; t < thi; ++t) {
        const float Fv = Fs[(t - c * CHUNK) * C_ + j];  // same drain as a_sh reads
        const int mc = mk_sh[t];                        // broadcast read
        // full 32-term fma sum from LDS (R4-validated association)
        float4 q = *(const float4*)&a_sh[0];
        float s0 = q.x * ET[0], s1 = q.y * ET[1], s2 = q.z * ET[2], s3 = q.w * ET[3];
#pragma unroll
        for (int g = 1; g < 8; ++g) {
          q = *(const float4*)&a_sh[g * 4];
          s0 = fmaf(q.x, ET[4 * g + 0], s0);
          s1 = fmaf(q.y, ET[4 * g + 1], s1);
          s2 = fmaf(q.z, ET[4 * g + 2], s2);
          s3 = fmaf(q.w, ET[4 * g + 3], s3);
        }
        const float sv = (s0 + s1) + (s2 + s3);
        const float s0b = bcast0(sv);            // lane 0 holds j=0 -> s_0
        const float r = __builtin_amdgcn_rcpf(s0b);
        const float pn = sv * r * Fv;
        vp = (mc > 0) ? pn : vp;
        if (tid == 0) s0_sh[t] = (mc > 0) ? s0b : 1.0f;  // single-lane store
        a_sh[j] = vp;                            // 2-way dup write, same value
      }
      if (c < NCHUNK - 1) {
#pragma unroll
        for (int i = 0; i < 8; ++i) {
          const float b0v = rlane(pre[i], 0);
          const float b1v = rlane(pre[i], 32);
          const float base = (tid < 32) ? b0v : b1v;
          Lsh[(c & 1) ^ 1][i * 64 + tid] = __expf(pre[i] - base);
        }
      }
    }
    // reconstruct m_T = m0 + sum_{t>=1, masked}(log s0_t + lc_t[0])  (R5)
    float lsum = 0.f, csum = 0.f;
#pragma unroll
    for (int kk = 0; kk < 8; ++kk) {
      const int t = tid + kk * 64;
      if (t >= 1) {
        lsum += __logf(s0_sh[t]);  // s0_sh[t]=1 when masked-out -> log 0
        if (mk_sh[t] > 0) csum += L[(size_t)t * C_];
      }
    }
#pragma unroll
    for (int d = 32; d; d >>= 1) { lsum += __shfl_xor(lsum, d); csum += __shfl_xor(csum, d); }
    const float mT = m0 + lsum + csum;
    float val = (tid < 32) ? (mT + __logf(vp) + et[j]) : NEG_INF;
    float mm = val;
#pragma unroll
    for (int d = 32; d; d >>= 1) mm = fmaxf(mm, __shfl_xor(mm, d));
    float ee = __expf(val - mm);
#pragma unroll
    for (int d = 32; d; d >>= 1) ee += __shfl_xor(ee, d);
    const float logZ = mm + __logf(ee);
    float sc = 0.f, msf = 0.f;
#pragma unroll
    for (int kk = 0; kk < 8; ++kk) {
      const int t = tid + kk * 64;
      const float mf = (float)mk_sh[t];
      const int tg = tgt[b * T_ + t];
      msf += mf;
      float contrib = 0.f;
      if (t >= 1) contrib += trans[tgt[b * T_ + t - 1] * C_ + tg];
      if (t <= T_ - 2) contrib += L[t * C_ + tg];
      sc = fmaf(mf, contrib, sc);
    }
#pragma unroll
    for (int d = 32; d; d >>= 1) { sc += __shfl_xor(sc, d); msf += __shfl_xor(msf, d); }
    if (tid == 0) {
      int last_idx = (int)msf - 1;
      if (last_idx < 0) last_idx = 0;
      const int lt = tgt[b * T_ + last_idx];
      float s = sc + st[tgt[b * T_]] + et[lt];
      s = fmaf((float)mk_sh[T_ - 1], L[(T_ - 1) * C_ + lt], s);
      wsp[b] = logZ;
      wsp[64 + b] = s;
      wsp[128 + b] = msf;
    }
  } else {
    // ================= Viterbi (values-only serial + parallel bp) ==========
    float TT[32];
#pragma unroll
    for (int i = 0; i < 32; ++i) TT[i] = trans[i * C_ + j];
#pragma unroll
    for (int i = 0; i < 8; ++i) Lsh[0][i * 64 + tid] = pre[i];  // raw chunk 0
    float vdj = st[j] + L[j];
    dsh[j] = vdj;  // ring row 0 = delta_0 (2-way dup write, same value)

    // parallel bp recompute (R5-validated): 2 t per iteration via h.
    // Descending '>=' scan == np.argmax first-index tie-break; candidate
    // values = plain f32 add delta+TT, bit-equal to the serial loop's.
    auto phase2 = [&](int tb) {
#pragma unroll 2
      for (int it = 0; it < 128; ++it) {
        const int t = tb + 2 * it + h;
        if (t < T_) {
          const float* dr = &dsh[((t - 1) & 255) * C_];
          float best; int idx;
          {
            float4 q = *(const float4*)&dr[28];
            best = q.w + TT[31]; idx = 31;
            float cx = q.z + TT[30]; bool ge = cx >= best; best = ge ? cx : best; idx = ge ? 30 : idx;
            cx = q.y + TT[29]; ge = cx >= best; best = ge ? cx : best; idx = ge ? 29 : idx;
            cx = q.x + TT[28]; ge = cx >= best; best = ge ? cx : best; idx = ge ? 28 : idx;
          }
#pragma unroll
          for (int g = 6; g >= 0; --g) {
            float4 q = *(const float4*)&dr[4 * g];
            float cx = q.w + TT[4 * g + 3]; bool ge = cx >= best; best = ge ? cx : best; idx = ge ? 4 * g + 3 : idx;
            cx = q.z + TT[4 * g + 2]; ge = cx >= best; best = ge ? cx : best; idx = ge ? 4 * g + 2 : idx;
            cx = q.y + TT[4 * g + 1]; ge = cx >= best; best = ge ? cx : best; idx = ge ? 4 * g + 1 : idx;
            cx = q.x + TT[4 * g + 0]; ge = cx >= best; best = ge ? cx : best; idx = ge ? 4 * g + 0 : idx;
          }
          const int bpv = (mk_sh[t] > 0) ? idx : j;
          bp[(t - 1) * C_ + j] = (unsigned char)bpv;
        }
      }
    };

    for (int c = 0; c < NCHUNK; ++c) {
      if (c < NCHUNK - 1) {
#pragma unroll
        for (int i = 0; i < 8; ++i) pre[i] = L[(c + 1) * (CHUNK * C_) + i * 64 + tid];
      }
      const float* Ls = Lsh[c & 1];
      const int tlo = c ? c * CHUNK : 1;
      const int thi = c * CHUNK + CHUNK;
      for (int t = tlo; t < thi; ++t) {
        const float lc = Ls[(t - c * CHUNK) * C_ + j];  // same drain as ring reads
        const int mc = mk_sh[t];                        // broadcast read
        const float* dr = &dsh[((t - 1) & 255) * C_];
        // VALUES ONLY: 32 plain f32 adds (np rounding) + exact fmax tree
        // (max is exactly associative -> bit-equal to np's sequential max).
        float gm[8];
#pragma unroll
        for (int g = 0; g < 8; ++g) {
          float4 q = *(const float4*)&dr[4 * g];
          const float c0 = q.x + TT[4 * g + 0];
          const float c1 = q.y + TT[4 * g + 1];
          const float c2 = q.z + TT[4 * g + 2];
          const float c3 = q.w + TT[4 * g + 3];
          gm[g] = fmaxf(fmaxf(c0, c1), fmaxf(c2, c3));
        }
        const float m01 = fmaxf(gm[0], gm[1]), m23 = fmaxf(gm[2], gm[3]);
        const float m45 = fmaxf(gm[4], gm[5]), m67 = fmaxf(gm[6], gm[7]);
        const float bestv = fmaxf(fmaxf(m01, m23), fmaxf(m45, m67));
        vdj = (mc > 0) ? (bestv + lc) : vdj;  // f32 add: matches np best+lt
        dsh[(t & 255) * C_ + j] = vdj;        // ring store (2-way dup, same value)
      }
      if (c < NCHUNK - 1) {
#pragma unroll
        for (int i = 0; i < 8; ++i) Lsh[(c & 1) ^ 1][i * 64 + tid] = pre[i];
      }
      if (c == 15) phase2(1);    // bp for t=1..256 from ring rows 0..255
    }
    phase2(257);                 // bp for t=257..511 (rows hold delta_256..510)

    // final argmax (first-index tie-break) + path score — f32 elementwise
    float fv = (tid < 32) ? (vdj + et[j]) : NEG_INF;
    int fi = (tid < 32) ? j : 64;
#pragma unroll
    for (int d = 32; d; d >>= 1) {
      const float ov = __shfl_xor(fv, d);
      const int oi = __shfl_xor(fi, d);
      if (ov > fv || (ov == fv && oi < fi)) { fv = ov; fi = oi; }
    }
    const int last_tag = fi;
    if (tid == 0) path_out[b] = fv;
    // ---- backtrace: 8-step jump maps (validated) ----
    int cur[32];
#pragma unroll
    for (int e = 0; e < 32; ++e) cur[e] = (tid + 64 * e) & 31;
#pragma unroll
    for (int s = 0; s < 8; ++s) {
#pragma unroll
      for (int e = 0; e < 32; ++e) {
        const int m = (tid + 64 * e) >> 5;
        const int r = 8 * m + 7 - s;
        if (r <= T_ - 2) cur[e] = bp[r * C_ + cur[e]];
      }
    }
#pragma unroll
    for (int e = 0; e < 32; ++e) c8[tid + 64 * e] = (unsigned char)cur[e];
    if (tid == 0) {
      int c = last_tag;
      tagb[T_ - 1] = (unsigned char)c;
      for (int m = 63; m >= 0; --m) { c = c8[m * C_ + c]; btag[m] = c; }  // btag[m]=tag_{8m}
    }
    {
      const int m = tid;
      const int rhi = (m == 63) ? (T_ - 2) : (8 * m + 7);
      int c = (m == 63) ? last_tag : btag[m + 1];
#pragma unroll
      for (int s = 0; s < 7; ++s) {
        const int r = rhi - s;
        if (r >= 8 * m + 1) { c = bp[r * C_ + c]; tagb[r] = (unsigned char)c; }
      }
      tagb[8 * m] = (unsigned char)btag[m];
    }
#pragma unroll
    for (int kk = 0; kk < 8; ++kk) {
      const int t = tid + kk * 64;
      tags_out[b * T_ + t] = (float)tagb[t];
    }
  }
}

// ---------------- loss reduction ----------------
__global__ __launch_bounds__(64) void k_loss(const float* __restrict__ wsp, float* __restrict__ out0) {
  const int tid = threadIdx.x;
  float d = wsp[64 + tid] - wsp[tid];
  float m = wsp[128 + tid];
#pragma unroll
  for (int s = 32; s; s >>= 1) { d += __shfl_xor(d, s); m += __shfl_xor(m, s); }
  if (tid == 0) out0[0] = -d / m;
}

extern "C" void kernel_launch(void* const* d_in, const int* in_sizes, int n_in,
                              void* d_out, int out_size, void* d_ws, size_t ws_size,
                              hipStream_t stream) {
  (void)in_sizes; (void)n_in; (void)out_size; (void)ws_size;
  const float* vec  = (const float*)d_in[0];
  const int* mask   = (const int*)d_in[1];
  const int* tgt    = (const int*)d_in[2];
  const float* W    = (const float*)d_in[3];
  const float* bias = (const float*)d_in[4];
  const float* tr   = (const float*)d_in[5];
  const float* st   = (const float*)d_in[6];
  const float* et   = (const float*)d_in[7];
  float* out = (float*)d_out;
  float* logits = out + 1;
  float* tags = out + 1 + (size_t)B_ * T_ * C_;
  float* path = tags + (size_t)B_ * T_;
  float* wsp = (float*)d_ws;  // [0,64): logZ  [64,128): score  [128,192): mask-sum

  hipLaunchKernelGGL(k_logits, dim3(512), dim3(256), 0, stream, vec, W, bias, logits);
  hipLaunchKernelGGL(k_crf, dim3(128), dim3(64), 0, stream, logits, mask, tgt, tr, st, et, wsp, tags, path);
  hipLaunchKernelGGL(k_loss, dim3(1), dim3(64), 0, stream, wsp, out);
}